// Round 6
// baseline (379.755 us; speedup 1.0000x reference)
//
#include <hip/hip_runtime.h>

#define SEQ 2048
#define NH 16
#define HD 64
#define DMODEL 1024

typedef short bf16x8 __attribute__((ext_vector_type(8)));
typedef float f32x16 __attribute__((ext_vector_type(16)));

union FragU {
    bf16x8 v;
    uint2 u2[2];
    unsigned int w[4];
    unsigned short s[8];
};

// Pack two f32 -> packed bf16 pair (lo in low 16 bits).
#if __has_builtin(__builtin_amdgcn_cvt_pk_bf16_f32)
typedef __bf16 v2bf_t __attribute__((ext_vector_type(2)));
__device__ __forceinline__ unsigned int pack_bf16(float lo, float hi) {
    union { v2bf_t h; unsigned int u; } cv;
    cv.h = __builtin_amdgcn_cvt_pk_bf16_f32(lo, hi);
    return cv.u;
}
#else
__device__ __forceinline__ unsigned int pack_bf16(float lo, float hi) {
    unsigned int a = __float_as_uint(lo) + 0x8000u;
    unsigned int b = __float_as_uint(hi) + 0x8000u;
    return __builtin_amdgcn_perm(b, a, 0x07060302);  // {b.hi16, a.hi16}
}
#endif

#define EXP_SCALE 1.44269504f   // 1/ln2, folded into Q and bias table
#define LN2       0.69314718f   // folded into epilogue store

// K tile stride (shorts): 68  (reads 2-way bank alias — free)
// V^T tile stride (shorts): 138 (69 dw = 5 mod 32 -> vf b64 reads conflict-free)
#define KST 68
#define VST 138

// Block: 512 threads = 8 waves; each wave computes a 32q x 64d output tile
// (block covers 256 q for one (b,h)).
// BK=128 (16 iters, HALF the barriers vs round 4). Each iter = two 64-kc
// sub-bodies identical to the round-4 proven body (QK 2 interleaved chains ->
// silu(s0) -> PV(s0) -> silu(s1) -> PV(s1)), with ONE __syncthreads at the
// end. K loads for tile t+1 issued at iter start, V loads at the u=1
// boundary; pack+ds_write late in u=1.
__global__ __launch_bounds__(512, 4)
void paa_kernel(const float* __restrict__ Vg, const float* __restrict__ Kg,
                const float* __restrict__ Qg, const float* __restrict__ RW,
                float* __restrict__ Og)
{
    __shared__ __align__(16) unsigned short KsLds[2][128 * KST];  // [kc][d]
    __shared__ __align__(16) unsigned short VtLds[2][64 * VST];   // [d][kc]
    __shared__ float btab[128];  // 1.4427*bias by distance, clamped at 127

    const int tid  = threadIdx.x;
    const int lane = tid & 63;
    const int wave = tid >> 6;   // 0..7
    const int half = lane >> 5;
    const int l31  = lane & 31;

    const int bid  = blockIdx.x;
    const int bh   = bid & 63;
    const int qt   = bid >> 6;   // 0..7
    const int b    = bh >> 4;
    const int head = bh & 15;

    const int q0w = qt * 256 + wave * 32;   // 32 q rows per wave

    // ---- bias table (pre-scaled by 1/ln2) ----
    if (tid < 128) {
        int rp = tid;
        int bucket;
        if (rp < 16) bucket = rp;
        else {
            int big = 16 + (int)(logf((float)rp * 0.0625f) * 7.6943736f); // 16/ln(8)
            bucket = big < 31 ? big : 31;
        }
        btab[tid] = RW[bucket * NH + head] * EXP_SCALE;
    }

    // ---- preload Q fragments (B operand of S^T), pre-scaled by 1/ln2 ----
    FragU qf[4];
    {
        const float* qrow = Qg + (size_t)(b * SEQ + q0w + l31) * DMODEL + head * HD;
        #pragma unroll
        for (int kf = 0; kf < 4; ++kf) {
            int dd = kf * 16 + half * 8;
            float4 x0 = *(const float4*)(qrow + dd);
            float4 x1 = *(const float4*)(qrow + dd + 4);
            FragU f;
            f.w[0] = pack_bf16(x0.x * EXP_SCALE, x0.y * EXP_SCALE);
            f.w[1] = pack_bf16(x0.z * EXP_SCALE, x0.w * EXP_SCALE);
            f.w[2] = pack_bf16(x1.x * EXP_SCALE, x1.y * EXP_SCALE);
            f.w[3] = pack_bf16(x1.z * EXP_SCALE, x1.w * EXP_SCALE);
            qf[kf] = f;
        }
    }

    f32x16 oacc[2];
    #pragma unroll
    for (int n = 0; n < 2; ++n)
        #pragma unroll
        for (int r = 0; r < 16; ++r) oacc[n][r] = 0.0f;

    // staging geometry (512 threads stage a 128x64 tile of K and of V)
    const int krow = tid >> 4;   // K: rows krow + 32*i, i=0..3
    const int c4   = tid & 15;   // K: 4 d cols at c4*4
    const int kc2  = tid >> 4;   // V: kc pairs at j*64 + kc2*2, j=0..1
    const int d4   = tid & 15;   // V: 4 d cols at d4*4

    const float* kp = Kg + (size_t)(b * SEQ + krow) * DMODEL + head * HD + c4 * 4;
    const float* vp = Vg + (size_t)(b * SEQ + kc2 * 2) * DMODEL + head * HD + d4 * 4;

    // ---- prologue: stage tile 0 into buffer 0 ----
    {
        float4 kx0 = *(const float4*)(kp);
        float4 kx1 = *(const float4*)(kp + (size_t)32 * DMODEL);
        float4 kx2 = *(const float4*)(kp + (size_t)64 * DMODEL);
        float4 kx3 = *(const float4*)(kp + (size_t)96 * DMODEL);
        float4 va0 = *(const float4*)(vp);
        float4 vb0 = *(const float4*)(vp + DMODEL);
        float4 va1 = *(const float4*)(vp + (size_t)64 * DMODEL);
        float4 vb1 = *(const float4*)(vp + (size_t)64 * DMODEL + DMODEL);
        kp += (size_t)128 * DMODEL;
        vp += (size_t)128 * DMODEL;
        uint2 w;
        w.x = pack_bf16(kx0.x, kx0.y); w.y = pack_bf16(kx0.z, kx0.w);
        *(uint2*)&KsLds[0][(krow +  0) * KST + c4 * 4] = w;
        w.x = pack_bf16(kx1.x, kx1.y); w.y = pack_bf16(kx1.z, kx1.w);
        *(uint2*)&KsLds[0][(krow + 32) * KST + c4 * 4] = w;
        w.x = pack_bf16(kx2.x, kx2.y); w.y = pack_bf16(kx2.z, kx2.w);
        *(uint2*)&KsLds[0][(krow + 64) * KST + c4 * 4] = w;
        w.x = pack_bf16(kx3.x, kx3.y); w.y = pack_bf16(kx3.z, kx3.w);
        *(uint2*)&KsLds[0][(krow + 96) * KST + c4 * 4] = w;
        *(unsigned int*)&VtLds[0][(d4 * 4 + 0) * VST + kc2 * 2]      = pack_bf16(va0.x, vb0.x);
        *(unsigned int*)&VtLds[0][(d4 * 4 + 1) * VST + kc2 * 2]      = pack_bf16(va0.y, vb0.y);
        *(unsigned int*)&VtLds[0][(d4 * 4 + 2) * VST + kc2 * 2]      = pack_bf16(va0.z, vb0.z);
        *(unsigned int*)&VtLds[0][(d4 * 4 + 3) * VST + kc2 * 2]      = pack_bf16(va0.w, vb0.w);
        *(unsigned int*)&VtLds[0][(d4 * 4 + 0) * VST + 64 + kc2 * 2] = pack_bf16(va1.x, vb1.x);
        *(unsigned int*)&VtLds[0][(d4 * 4 + 1) * VST + 64 + kc2 * 2] = pack_bf16(va1.y, vb1.y);
        *(unsigned int*)&VtLds[0][(d4 * 4 + 2) * VST + 64 + kc2 * 2] = pack_bf16(va1.z, vb1.z);
        *(unsigned int*)&VtLds[0][(d4 * 4 + 3) * VST + 64 + kc2 * 2] = pack_bf16(va1.w, vb1.w);
    }
    __syncthreads();

    const float bias_d0  = btab[0];    // all d <= 0  -> bucket 0
    const float bias_far = btab[127];  // all d >= 113 -> bucket 31

    // QK two interleaved chains for one 64-kc sub-tile at row base ubase,
    // absolute kc base kcb_u (for bias selection).
    auto qk2 = [&](const unsigned short* Ks, int ubase, int kcb_u,
                   f32x16& s0, f32x16& s1) {
        #pragma unroll
        for (int t = 0; t < 2; ++t) {
            f32x16& st = t ? s1 : s0;
            const int kcmin = kcb_u + t * 32;
            if (q0w + 31 - kcmin <= 0) {               // whole tile d<=0
                #pragma unroll
                for (int r = 0; r < 16; ++r) st[r] = bias_d0;
            } else if (q0w - (kcmin + 31) >= 113) {    // whole tile bucket 31
                #pragma unroll
                for (int r = 0; r < 16; ++r) st[r] = bias_far;
            } else {                                   // mixed band (~9% of tiles)
                const int dql = q0w + l31 - kcmin - 4 * half;
                #pragma unroll
                for (int r = 0; r < 16; ++r) {
                    int dv = dql - ((r & 3) + 8 * (r >> 2));
                    dv = dv < 0 ? 0 : (dv > 127 ? 127 : dv);
                    st[r] = btab[dv];
                }
            }
        }
        __builtin_amdgcn_s_setprio(1);
        #pragma unroll
        for (int kf = 0; kf < 4; ++kf) {
            FragU ka0, ka1;
            int off = (ubase + l31) * KST + kf * 16 + half * 8;
            ka0.u2[0] = *(const uint2*)&Ks[off];
            ka0.u2[1] = *(const uint2*)&Ks[off + 4];
            off += 32 * KST;
            ka1.u2[0] = *(const uint2*)&Ks[off];
            ka1.u2[1] = *(const uint2*)&Ks[off + 4];
            s0 = __builtin_amdgcn_mfma_f32_32x32x16_bf16(ka0.v, qf[kf].v, s0, 0, 0, 0);
            s1 = __builtin_amdgcn_mfma_f32_32x32x16_bf16(ka1.v, qf[kf].v, s1, 0, 0, 0);
        }
        __builtin_amdgcn_s_setprio(0);
    };

    auto siluPack = [&](const f32x16& st, FragU& lo, FragU& hi) {
        float vals[16];
        #pragma unroll
        for (int r = 0; r < 16; ++r) {
            float x = st[r];
            float e = __builtin_amdgcn_exp2f(-x);
            vals[r] = x * __builtin_amdgcn_rcpf(1.0f + e);
        }
        #pragma unroll
        for (int j = 0; j < 4; ++j) lo.w[j] = pack_bf16(vals[2 * j], vals[2 * j + 1]);
        #pragma unroll
        for (int j = 0; j < 4; ++j) hi.w[j] = pack_bf16(vals[8 + 2 * j], vals[9 + 2 * j]);
    };

    auto pv1 = [&](const unsigned short* Vt, int ubase, int fbase, const FragU& pf) {
        #pragma unroll
        for (int n = 0; n < 2; ++n) {
            FragU vf;
            int off = (n * 32 + l31) * VST + ubase + fbase * 16 + half * 4;
            vf.u2[0] = *(const uint2*)&Vt[off];      // kc offsets 4h..4h+3
            vf.u2[1] = *(const uint2*)&Vt[off + 8];  // kc offsets 4h+8..4h+11
            oacc[n] = __builtin_amdgcn_mfma_f32_32x32x16_bf16(pf.v, vf.v, oacc[n], 0, 0, 0);
        }
    };

    #pragma unroll 2
    for (int it = 0; it < 16; ++it) {
        const int cur = it & 1;
        const int kcb = it * 128;
        const unsigned short* Ks = KsLds[cur];
        const unsigned short* Vt = VtLds[cur];
        const bool pre = (it < 15);

        // ---- issue next-tile K loads EARLY (hide under u=0 compute) ----
        float4 kx0, kx1, kx2, kx3;
        if (pre) {
            kx0 = *(const float4*)(kp);
            kx1 = *(const float4*)(kp + (size_t)32 * DMODEL);
            kx2 = *(const float4*)(kp + (size_t)64 * DMODEL);
            kx3 = *(const float4*)(kp + (size_t)96 * DMODEL);
            kp += (size_t)128 * DMODEL;
        }

        FragU pf0, pf1, pf2, pf3;
        f32x16 s0, s1;

        // ================= u = 0 : kc [kcb, kcb+64) =================
        qk2(Ks, 0, kcb, s0, s1);
        siluPack(s0, pf0, pf1);
        pv1(Vt, 0, 0, pf0);
        pv1(Vt, 0, 1, pf1);
        siluPack(s1, pf2, pf3);
        pv1(Vt, 0, 2, pf2);
        pv1(Vt, 0, 3, pf3);

        // ---- issue next-tile V loads (hide under u=1 QK/silu/PV) ----
        float4 va0, vb0, va1, vb1;
        if (pre) {
            va0 = *(const float4*)(vp);
            vb0 = *(const float4*)(vp + DMODEL);
            va1 = *(const float4*)(vp + (size_t)64 * DMODEL);
            vb1 = *(const float4*)(vp + (size_t)64 * DMODEL + DMODEL);
            vp += (size_t)128 * DMODEL;
        }

        // ================= u = 1 : kc [kcb+64, kcb+128) =================
        qk2(Ks, 64, kcb + 64, s0, s1);
        siluPack(s0, pf0, pf1);
        pv1(Vt, 64, 0, pf0);
        pv1(Vt, 64, 1, pf1);

        // ---- pack + ds_write next tile into the other buffer (loads long done) ----
        if (pre) {
            const int nb = cur ^ 1;
            uint2 w;
            w.x = pack_bf16(kx0.x, kx0.y); w.y = pack_bf16(kx0.z, kx0.w);
            *(uint2*)&KsLds[nb][(krow +  0) * KST + c4 * 4] = w;
            w.x = pack_bf16(kx1.x, kx1.y); w.y = pack_bf16(kx1.z, kx1.w);
            *(uint2*)&KsLds[nb][(krow + 32) * KST + c4 * 4] = w;
            w.x = pack_bf16(kx2.x, kx2.y); w.y = pack_bf16(kx2.z, kx2.w);
            *(uint2*)&KsLds[nb][(krow + 64) * KST + c4 * 4] = w;
            w.x = pack_bf16(kx3.x, kx3.y); w.y = pack_bf16(kx3.z, kx3.w);
            *(uint2*)&KsLds[nb][(krow + 96) * KST + c4 * 4] = w;
            *(unsigned int*)&VtLds[nb][(d4 * 4 + 0) * VST + kc2 * 2]      = pack_bf16(va0.x, vb0.x);
            *(unsigned int*)&VtLds[nb][(d4 * 4 + 1) * VST + kc2 * 2]      = pack_bf16(va0.y, vb0.y);
            *(unsigned int*)&VtLds[nb][(d4 * 4 + 2) * VST + kc2 * 2]      = pack_bf16(va0.z, vb0.z);
            *(unsigned int*)&VtLds[nb][(d4 * 4 + 3) * VST + kc2 * 2]      = pack_bf16(va0.w, vb0.w);
            *(unsigned int*)&VtLds[nb][(d4 * 4 + 0) * VST + 64 + kc2 * 2] = pack_bf16(va1.x, vb1.x);
            *(unsigned int*)&VtLds[nb][(d4 * 4 + 1) * VST + 64 + kc2 * 2] = pack_bf16(va1.y, vb1.y);
            *(unsigned int*)&VtLds[nb][(d4 * 4 + 2) * VST + 64 + kc2 * 2] = pack_bf16(va1.z, vb1.z);
            *(unsigned int*)&VtLds[nb][(d4 * 4 + 3) * VST + 64 + kc2 * 2] = pack_bf16(va1.w, vb1.w);
        }

        siluPack(s1, pf2, pf3);
        pv1(Vt, 64, 2, pf2);
        pv1(Vt, 64, 3, pf3);

        // ---- single barrier per 128-kc iter ----
        if (pre) __syncthreads();
    }

    // ---- store (x ln2): C layout row=q_local, col=d_local ----
    float* obase = Og + (size_t)(b * SEQ) * DMODEL + head * HD;
    #pragma unroll
    for (int r = 0; r < 16; ++r) {
        int q = q0w + (r & 3) + 8 * (r >> 2) + 4 * half;
        float* orow = obase + (size_t)q * DMODEL;
        #pragma unroll
        for (int n = 0; n < 2; ++n)
            orow[n * 32 + l31] = oacc[n][r] * LN2;
    }
}

extern "C" void kernel_launch(void* const* d_in, const int* in_sizes, int n_in,
                              void* d_out, int out_size, void* d_ws, size_t ws_size,
                              hipStream_t stream) {
    const float* v  = (const float*)d_in[0];
    const float* k  = (const float*)d_in[1];
    const float* q  = (const float*)d_in[2];
    const float* rw = (const float*)d_in[3];
    float* out = (float*)d_out;
    paa_kernel<<<dim3(512), dim3(512), 0, stream>>>(v, k, q, rw, out);
}

// Round 7
// 305.536 us; speedup vs baseline: 1.2429x; 1.2429x over previous
//
#include <hip/hip_runtime.h>

#define SEQ 2048
#define NH 16
#define HD 64
#define DMODEL 1024

typedef short bf16x8 __attribute__((ext_vector_type(8)));
typedef float f32x16 __attribute__((ext_vector_type(16)));

union FragU {
    bf16x8 v;
    uint2 u2[2];
    unsigned int w[4];
    unsigned short s[8];
};

// Pack two f32 -> packed bf16 pair (lo in low 16 bits).
#if __has_builtin(__builtin_amdgcn_cvt_pk_bf16_f32)
typedef __bf16 v2bf_t __attribute__((ext_vector_type(2)));
__device__ __forceinline__ unsigned int pack_bf16(float lo, float hi) {
    union { v2bf_t h; unsigned int u; } cv;
    cv.h = __builtin_amdgcn_cvt_pk_bf16_f32(lo, hi);
    return cv.u;
}
#else
__device__ __forceinline__ unsigned int pack_bf16(float lo, float hi) {
    unsigned int a = __float_as_uint(lo) + 0x8000u;
    unsigned int b = __float_as_uint(hi) + 0x8000u;
    return __builtin_amdgcn_perm(b, a, 0x07060302);  // {b.hi16, a.hi16}
}
#endif

#define EXP_SCALE 1.44269504f   // 1/ln2, folded into Q and bias table
#define LN2       0.69314718f   // folded into epilogue store

// Block: 512 threads = 8 waves; each wave computes a 32q x 64d output tile
// (block covers 256 q for one (b,h)).
// Structure = round-4 proven body (126.5us) + T15 half-iter software pipeline:
// silu(s1)+PV(s1) of iter t are DEFERRED across the barrier into iter t+1,
// so every post-barrier phase starts with pure-register trans work (covers
// LDS ka-load latency) and PV(prev) MFMAs overlap the next QK's LDS reads.
// V is TRIPLE-buffered (finish(t-1) reads V[t-1] while iter t stages V[t+1]);
// K stays double-buffered. Register budget kept at R4 level (BK=128 in round
// 6 spilled to scratch and ran 2.4x slower — hard cap ~128 VGPR at 4 w/SIMD).
__global__ __launch_bounds__(512, 4)
void paa_kernel(const float* __restrict__ Vg, const float* __restrict__ Kg,
                const float* __restrict__ Qg, const float* __restrict__ RW,
                float* __restrict__ Og)
{
    __shared__ __align__(16) unsigned short KsLds[2][64 * 68];  // [kc][d], stride 68
    __shared__ __align__(16) unsigned short VtLds[3][64 * 68];  // [d][kc], stride 68
    __shared__ float btab[128];  // 1.4427*bias by distance, clamped at 127

    const int tid  = threadIdx.x;
    const int lane = tid & 63;
    const int wave = tid >> 6;   // 0..7
    const int half = lane >> 5;
    const int l31  = lane & 31;

    const int bid  = blockIdx.x;
    const int bh   = bid & 63;
    const int qt   = bid >> 6;   // 0..7
    const int b    = bh >> 4;
    const int head = bh & 15;

    const int q0w = qt * 256 + wave * 32;   // 32 q rows per wave

    // ---- bias table (pre-scaled by 1/ln2) ----
    if (tid < 128) {
        int rp = tid;
        int bucket;
        if (rp < 16) bucket = rp;
        else {
            int big = 16 + (int)(logf((float)rp * 0.0625f) * 7.6943736f); // 16/ln(8)
            bucket = big < 31 ? big : 31;
        }
        btab[tid] = RW[bucket * NH + head] * EXP_SCALE;
    }

    // ---- preload Q fragments (B operand of S^T), pre-scaled by 1/ln2 ----
    FragU qf[4];
    {
        const float* qrow = Qg + (size_t)(b * SEQ + q0w + l31) * DMODEL + head * HD;
        #pragma unroll
        for (int kf = 0; kf < 4; ++kf) {
            int dd = kf * 16 + half * 8;
            float4 x0 = *(const float4*)(qrow + dd);
            float4 x1 = *(const float4*)(qrow + dd + 4);
            FragU f;
            f.w[0] = pack_bf16(x0.x * EXP_SCALE, x0.y * EXP_SCALE);
            f.w[1] = pack_bf16(x0.z * EXP_SCALE, x0.w * EXP_SCALE);
            f.w[2] = pack_bf16(x1.x * EXP_SCALE, x1.y * EXP_SCALE);
            f.w[3] = pack_bf16(x1.z * EXP_SCALE, x1.w * EXP_SCALE);
            qf[kf] = f;
        }
    }

    f32x16 oacc[2];
    #pragma unroll
    for (int n = 0; n < 2; ++n)
        #pragma unroll
        for (int r = 0; r < 16; ++r) oacc[n][r] = 0.0f;

    // staging geometry (512 threads stage a 64x64 tile of K and of V)
    const int krow = tid >> 4;   // 0..31 (+32 for second half)
    const int c4   = tid & 15;
    const int kc2  = tid >> 4;   // V: 2 kc rows at kc2*2
    const int d4   = tid & 15;   // V: 4 d cols at d4*4

    const float* kp = Kg + (size_t)(b * SEQ + krow) * DMODEL + head * HD + c4 * 4;
    const float* vp = Vg + (size_t)(b * SEQ + kc2 * 2) * DMODEL + head * HD + d4 * 4;

    // ---- prologue: stage tile 0 into K buffer 0 / V buffer 0 ----
    {
        float4 k0 = *(const float4*)(kp);
        float4 k1 = *(const float4*)(kp + (size_t)32 * DMODEL);
        float4 v0 = *(const float4*)(vp);
        float4 v1 = *(const float4*)(vp + DMODEL);
        kp += (size_t)64 * DMODEL;
        vp += (size_t)64 * DMODEL;
        uint2 w;
        w.x = pack_bf16(k0.x, k0.y); w.y = pack_bf16(k0.z, k0.w);
        *(uint2*)&KsLds[0][krow * 68 + c4 * 4] = w;
        w.x = pack_bf16(k1.x, k1.y); w.y = pack_bf16(k1.z, k1.w);
        *(uint2*)&KsLds[0][(krow + 32) * 68 + c4 * 4] = w;
        *(unsigned int*)&VtLds[0][(d4 * 4 + 0) * 68 + kc2 * 2] = pack_bf16(v0.x, v1.x);
        *(unsigned int*)&VtLds[0][(d4 * 4 + 1) * 68 + kc2 * 2] = pack_bf16(v0.y, v1.y);
        *(unsigned int*)&VtLds[0][(d4 * 4 + 2) * 68 + kc2 * 2] = pack_bf16(v0.z, v1.z);
        *(unsigned int*)&VtLds[0][(d4 * 4 + 3) * 68 + kc2 * 2] = pack_bf16(v0.w, v1.w);
    }
    __syncthreads();

    const float bias_d0  = btab[0];    // all d <= 0  -> bucket 0
    const float bias_far = btab[127];  // all d >= 113 -> bucket 31

    // rotating LDS tile pointers
    const unsigned short* Kc = KsLds[0];          // QK reads (tile t)
    unsigned short*       Kn = &KsLds[1][0];      // stage target (tile t+1)
    const unsigned short* Vprev = VtLds[2];       // finish reads (tile t-1), unused at t=0
    const unsigned short* Vc = VtLds[0];          // PV(s0) reads (tile t)
    unsigned short*       Vn = &VtLds[1][0];      // stage target (tile t+1)

    f32x16 s1c;  // s1 accumulator carried across the barrier (finished next iter)

    #pragma unroll 2
    for (int it = 0; it < 32; ++it) {
        const int kcb = it * 64;
        const bool pre = (it < 31);

        // ---- issue next-tile global loads EARLY (latency hides under compute) ----
        float4 k0, k1, v0, v1;
        if (pre) {
            k0 = *(const float4*)(kp);
            k1 = *(const float4*)(kp + (size_t)32 * DMODEL);
            v0 = *(const float4*)(vp);
            v1 = *(const float4*)(vp + DMODEL);
            kp += (size_t)64 * DMODEL;
            vp += (size_t)64 * DMODEL;
        }

        // ---- deferred finish of previous iter's s1: pure-register silu first
        //      (covers this iter's LDS latency), then PV into V[t-1] frags 2,3 ----
        if (it > 0) {
            float vals[16];
            #pragma unroll
            for (int r = 0; r < 16; ++r) {
                float x = s1c[r];
                float e = __builtin_amdgcn_exp2f(-x);
                vals[r] = x * __builtin_amdgcn_rcpf(1.0f + e);
            }
            FragU pfA, pfB;
            #pragma unroll
            for (int j = 0; j < 4; ++j) pfA.w[j] = pack_bf16(vals[2 * j], vals[2 * j + 1]);
            #pragma unroll
            for (int j = 0; j < 4; ++j) pfB.w[j] = pack_bf16(vals[8 + 2 * j], vals[9 + 2 * j]);
            #pragma unroll
            for (int n = 0; n < 2; ++n) {
                FragU vf;
                int off = (n * 32 + l31) * 68 + 32 + half * 4;
                vf.u2[0] = *(const uint2*)&Vprev[off];
                vf.u2[1] = *(const uint2*)&Vprev[off + 8];
                oacc[n] = __builtin_amdgcn_mfma_f32_32x32x16_bf16(pfA.v, vf.v, oacc[n], 0, 0, 0);
            }
            #pragma unroll
            for (int n = 0; n < 2; ++n) {
                FragU vf;
                int off = (n * 32 + l31) * 68 + 48 + half * 4;
                vf.u2[0] = *(const uint2*)&Vprev[off];
                vf.u2[1] = *(const uint2*)&Vprev[off + 8];
                oacc[n] = __builtin_amdgcn_mfma_f32_32x32x16_bf16(pfB.v, vf.v, oacc[n], 0, 0, 0);
            }
        }

        // ---- X^T = K * Q^T + bias (bias in accumulator init), two interleaved chains ----
        f32x16 s0;
        #pragma unroll
        for (int t = 0; t < 2; ++t) {
            f32x16& st = t ? s1c : s0;
            const int kcmin = kcb + t * 32;
            if (q0w + 31 - kcmin <= 0) {               // whole tile d<=0
                #pragma unroll
                for (int r = 0; r < 16; ++r) st[r] = bias_d0;
            } else if (q0w - (kcmin + 31) >= 113) {    // whole tile bucket 31
                #pragma unroll
                for (int r = 0; r < 16; ++r) st[r] = bias_far;
            } else {                                   // mixed band (~9% of tiles)
                const int dql = q0w + l31 - kcmin - 4 * half;
                #pragma unroll
                for (int r = 0; r < 16; ++r) {
                    int dv = dql - ((r & 3) + 8 * (r >> 2));
                    dv = dv < 0 ? 0 : (dv > 127 ? 127 : dv);
                    st[r] = btab[dv];
                }
            }
        }

        __builtin_amdgcn_s_setprio(1);
        #pragma unroll
        for (int kf = 0; kf < 4; ++kf) {
            FragU ka0, ka1;
            {
                int off = l31 * 68 + kf * 16 + half * 8;
                ka0.u2[0] = *(const uint2*)&Kc[off];
                ka0.u2[1] = *(const uint2*)&Kc[off + 4];
                off += 32 * 68;
                ka1.u2[0] = *(const uint2*)&Kc[off];
                ka1.u2[1] = *(const uint2*)&Kc[off + 4];
            }
            s0  = __builtin_amdgcn_mfma_f32_32x32x16_bf16(ka0.v, qf[kf].v, s0,  0, 0, 0);
            s1c = __builtin_amdgcn_mfma_f32_32x32x16_bf16(ka1.v, qf[kf].v, s1c, 0, 0, 0);
        }
        __builtin_amdgcn_s_setprio(0);

        // ---- finish s0 now: silu + PV into V[t] frags 0,1 ----
        {
            float vals[16];
            #pragma unroll
            for (int r = 0; r < 16; ++r) {
                float x = s0[r];
                float e = __builtin_amdgcn_exp2f(-x);
                vals[r] = x * __builtin_amdgcn_rcpf(1.0f + e);
            }
            FragU pf0, pf1;
            #pragma unroll
            for (int j = 0; j < 4; ++j) pf0.w[j] = pack_bf16(vals[2 * j], vals[2 * j + 1]);
            #pragma unroll
            for (int j = 0; j < 4; ++j) pf1.w[j] = pack_bf16(vals[8 + 2 * j], vals[9 + 2 * j]);
            #pragma unroll
            for (int n = 0; n < 2; ++n) {
                FragU vf;
                int off = (n * 32 + l31) * 68 + half * 4;
                vf.u2[0] = *(const uint2*)&Vc[off];
                vf.u2[1] = *(const uint2*)&Vc[off + 8];
                oacc[n] = __builtin_amdgcn_mfma_f32_32x32x16_bf16(pf0.v, vf.v, oacc[n], 0, 0, 0);
            }
            #pragma unroll
            for (int n = 0; n < 2; ++n) {
                FragU vf;
                int off = (n * 32 + l31) * 68 + 16 + half * 4;
                vf.u2[0] = *(const uint2*)&Vc[off];
                vf.u2[1] = *(const uint2*)&Vc[off + 8];
                oacc[n] = __builtin_amdgcn_mfma_f32_32x32x16_bf16(pf1.v, vf.v, oacc[n], 0, 0, 0);
            }
        }

        // ---- pack + ds_write next tile (loads long done) ----
        if (pre) {
            uint2 w;
            w.x = pack_bf16(k0.x, k0.y); w.y = pack_bf16(k0.z, k0.w);
            *(uint2*)&Kn[krow * 68 + c4 * 4] = w;
            w.x = pack_bf16(k1.x, k1.y); w.y = pack_bf16(k1.z, k1.w);
            *(uint2*)&Kn[(krow + 32) * 68 + c4 * 4] = w;
            *(unsigned int*)&Vn[(d4 * 4 + 0) * 68 + kc2 * 2] = pack_bf16(v0.x, v1.x);
            *(unsigned int*)&Vn[(d4 * 4 + 1) * 68 + kc2 * 2] = pack_bf16(v0.y, v1.y);
            *(unsigned int*)&Vn[(d4 * 4 + 2) * 68 + kc2 * 2] = pack_bf16(v0.z, v1.z);
            *(unsigned int*)&Vn[(d4 * 4 + 3) * 68 + kc2 * 2] = pack_bf16(v0.w, v1.w);
        }

        // ---- single barrier per iter: next buffers written, current reads done ----
        if (pre) __syncthreads();

        // ---- rotate tile pointers (K: 2-cycle, V: 3-cycle) ----
        {
            const unsigned short* tk = Kc; Kc = Kn; Kn = (unsigned short*)tk;
            const unsigned short* tv = Vprev; Vprev = Vc; Vc = Vn; Vn = (unsigned short*)tv;
        }
    }

    // ---- epilogue: finish the last iter's s1 (V tile 31 untouched after loop) ----
    {
        float vals[16];
        #pragma unroll
        for (int r = 0; r < 16; ++r) {
            float x = s1c[r];
            float e = __builtin_amdgcn_exp2f(-x);
            vals[r] = x * __builtin_amdgcn_rcpf(1.0f + e);
        }
        FragU pfA, pfB;
        #pragma unroll
        for (int j = 0; j < 4; ++j) pfA.w[j] = pack_bf16(vals[2 * j], vals[2 * j + 1]);
        #pragma unroll
        for (int j = 0; j < 4; ++j) pfB.w[j] = pack_bf16(vals[8 + 2 * j], vals[9 + 2 * j]);
        #pragma unroll
        for (int n = 0; n < 2; ++n) {
            FragU vf;
            int off = (n * 32 + l31) * 68 + 32 + half * 4;
            vf.u2[0] = *(const uint2*)&Vprev[off];
            vf.u2[1] = *(const uint2*)&Vprev[off + 8];
            oacc[n] = __builtin_amdgcn_mfma_f32_32x32x16_bf16(pfA.v, vf.v, oacc[n], 0, 0, 0);
        }
        #pragma unroll
        for (int n = 0; n < 2; ++n) {
            FragU vf;
            int off = (n * 32 + l31) * 68 + 48 + half * 4;
            vf.u2[0] = *(const uint2*)&Vprev[off];
            vf.u2[1] = *(const uint2*)&Vprev[off + 8];
            oacc[n] = __builtin_amdgcn_mfma_f32_32x32x16_bf16(pfB.v, vf.v, oacc[n], 0, 0, 0);
        }
    }

    // ---- store (x ln2): C layout row=q_local, col=d_local ----
    float* obase = Og + (size_t)(b * SEQ) * DMODEL + head * HD;
    #pragma unroll
    for (int r = 0; r < 16; ++r) {
        int q = q0w + (r & 3) + 8 * (r >> 2) + 4 * half;
        float* orow = obase + (size_t)q * DMODEL;
        #pragma unroll
        for (int n = 0; n < 2; ++n)
            orow[n * 32 + l31] = oacc[n][r] * LN2;
    }
}

extern "C" void kernel_launch(void* const* d_in, const int* in_sizes, int n_in,
                              void* d_out, int out_size, void* d_ws, size_t ws_size,
                              hipStream_t stream) {
    const float* v  = (const float*)d_in[0];
    const float* k  = (const float*)d_in[1];
    const float* q  = (const float*)d_in[2];
    const float* rw = (const float*)d_in[3];
    float* out = (float*)d_out;
    paa_kernel<<<dim3(512), dim3(512), 0, stream>>>(v, k, q, rw, out);
}

// Round 8
// 279.224 us; speedup vs baseline: 1.3600x; 1.0942x over previous
//
#include <hip/hip_runtime.h>

#define SEQ 2048
#define NH 16
#define HD 64
#define DMODEL 1024

typedef short bf16x8 __attribute__((ext_vector_type(8)));
typedef float f32x16 __attribute__((ext_vector_type(16)));

union FragU {
    bf16x8 v;
    uint2 u2[2];
    unsigned int w[4];
    unsigned short s[8];
};

// Pack two f32 -> packed bf16 pair (lo in low 16 bits).
#if __has_builtin(__builtin_amdgcn_cvt_pk_bf16_f32)
typedef __bf16 v2bf_t __attribute__((ext_vector_type(2)));
__device__ __forceinline__ unsigned int pack_bf16(float lo, float hi) {
    union { v2bf_t h; unsigned int u; } cv;
    cv.h = __builtin_amdgcn_cvt_pk_bf16_f32(lo, hi);
    return cv.u;
}
#else
__device__ __forceinline__ unsigned int pack_bf16(float lo, float hi) {
    unsigned int a = __float_as_uint(lo) + 0x8000u;
    unsigned int b = __float_as_uint(hi) + 0x8000u;
    return __builtin_amdgcn_perm(b, a, 0x07060302);  // {b.hi16, a.hi16}
}
#endif

#define EXP_SCALE 1.44269504f   // 1/ln2, folded into Q and bias table
#define LN2       0.69314718f   // folded into epilogue store

// Round-8: SAME per-wave body as round-4 (proven 126.5us), but 256-thread
// blocks (4 waves, 128 q rows) and grid=1024 -> 4 independent barrier
// domains per CU. Phase-locked waves were the idle source: the per-iter
// __syncthreads aligned all waves so trans bursts (silu) saturated the
// trans pipe while MFMA idled, alternately. Independent blocks drift
// anti-phase, overlapping one block's silu with another's MFMA/staging.
// Cost: staging per CU doubles (each thread stages 2x: 8 float4 loads,
// 16 packs). V loads issued mid-iter to cap prefetch register liveness
// (R6/R7 lesson: body liveness past ~128 regs spills -> WRITE_SIZE blowup).
__global__ __launch_bounds__(256, 4)
void paa_kernel(const float* __restrict__ Vg, const float* __restrict__ Kg,
                const float* __restrict__ Qg, const float* __restrict__ RW,
                float* __restrict__ Og)
{
    __shared__ __align__(16) unsigned short KsLds[2][64 * 68];  // [kc][d], stride 68
    __shared__ __align__(16) unsigned short VtLds[2][64 * 68];  // [d][kc], stride 68
    __shared__ float btab[128];  // 1.4427*bias by distance, clamped at 127

    const int tid  = threadIdx.x;
    const int lane = tid & 63;
    const int wave = tid >> 6;   // 0..3
    const int half = lane >> 5;
    const int l31  = lane & 31;

    const int bid  = blockIdx.x;
    const int bh   = bid & 63;
    const int qt   = bid >> 6;   // 0..15
    const int b    = bh >> 4;
    const int head = bh & 15;

    const int q0w = qt * 128 + wave * 32;   // 32 q rows per wave

    // ---- bias table (pre-scaled by 1/ln2) ----
    if (tid < 128) {
        int rp = tid;
        int bucket;
        if (rp < 16) bucket = rp;
        else {
            int big = 16 + (int)(logf((float)rp * 0.0625f) * 7.6943736f); // 16/ln(8)
            bucket = big < 31 ? big : 31;
        }
        btab[tid] = RW[bucket * NH + head] * EXP_SCALE;
    }

    // ---- preload Q fragments (B operand of S^T), pre-scaled by 1/ln2 ----
    FragU qf[4];
    {
        const float* qrow = Qg + (size_t)(b * SEQ + q0w + l31) * DMODEL + head * HD;
        #pragma unroll
        for (int kf = 0; kf < 4; ++kf) {
            int dd = kf * 16 + half * 8;
            float4 x0 = *(const float4*)(qrow + dd);
            float4 x1 = *(const float4*)(qrow + dd + 4);
            FragU f;
            f.w[0] = pack_bf16(x0.x * EXP_SCALE, x0.y * EXP_SCALE);
            f.w[1] = pack_bf16(x0.z * EXP_SCALE, x0.w * EXP_SCALE);
            f.w[2] = pack_bf16(x1.x * EXP_SCALE, x1.y * EXP_SCALE);
            f.w[3] = pack_bf16(x1.z * EXP_SCALE, x1.w * EXP_SCALE);
            qf[kf] = f;
        }
    }

    f32x16 oacc[2];
    #pragma unroll
    for (int n = 0; n < 2; ++n)
        #pragma unroll
        for (int r = 0; r < 16; ++r) oacc[n][r] = 0.0f;

    // staging geometry (256 threads stage a 64x64 tile of K and of V)
    const int krow = tid >> 4;   // K: rows krow + 16*i, i=0..3
    const int c4   = tid & 15;   // K: 4 d cols at c4*4
    const int kc2  = tid >> 4;   // V: kc pairs at kc2*2 and kc2*2+32
    const int d4   = tid & 15;   // V: 4 d cols at d4*4

    const float* kp = Kg + (size_t)(b * SEQ + krow) * DMODEL + head * HD + c4 * 4;
    const float* vp = Vg + (size_t)(b * SEQ + kc2 * 2) * DMODEL + head * HD + d4 * 4;

    // ---- prologue: stage tile 0 into buffer 0 ----
    {
        float4 kx0 = *(const float4*)(kp);
        float4 kx1 = *(const float4*)(kp + (size_t)16 * DMODEL);
        float4 kx2 = *(const float4*)(kp + (size_t)32 * DMODEL);
        float4 kx3 = *(const float4*)(kp + (size_t)48 * DMODEL);
        float4 va0 = *(const float4*)(vp);
        float4 vb0 = *(const float4*)(vp + DMODEL);
        float4 va1 = *(const float4*)(vp + (size_t)32 * DMODEL);
        float4 vb1 = *(const float4*)(vp + (size_t)32 * DMODEL + DMODEL);
        kp += (size_t)64 * DMODEL;
        vp += (size_t)64 * DMODEL;
        uint2 w;
        w.x = pack_bf16(kx0.x, kx0.y); w.y = pack_bf16(kx0.z, kx0.w);
        *(uint2*)&KsLds[0][(krow +  0) * 68 + c4 * 4] = w;
        w.x = pack_bf16(kx1.x, kx1.y); w.y = pack_bf16(kx1.z, kx1.w);
        *(uint2*)&KsLds[0][(krow + 16) * 68 + c4 * 4] = w;
        w.x = pack_bf16(kx2.x, kx2.y); w.y = pack_bf16(kx2.z, kx2.w);
        *(uint2*)&KsLds[0][(krow + 32) * 68 + c4 * 4] = w;
        w.x = pack_bf16(kx3.x, kx3.y); w.y = pack_bf16(kx3.z, kx3.w);
        *(uint2*)&KsLds[0][(krow + 48) * 68 + c4 * 4] = w;
        *(unsigned int*)&VtLds[0][(d4 * 4 + 0) * 68 + kc2 * 2]      = pack_bf16(va0.x, vb0.x);
        *(unsigned int*)&VtLds[0][(d4 * 4 + 1) * 68 + kc2 * 2]      = pack_bf16(va0.y, vb0.y);
        *(unsigned int*)&VtLds[0][(d4 * 4 + 2) * 68 + kc2 * 2]      = pack_bf16(va0.z, vb0.z);
        *(unsigned int*)&VtLds[0][(d4 * 4 + 3) * 68 + kc2 * 2]      = pack_bf16(va0.w, vb0.w);
        *(unsigned int*)&VtLds[0][(d4 * 4 + 0) * 68 + 32 + kc2 * 2] = pack_bf16(va1.x, vb1.x);
        *(unsigned int*)&VtLds[0][(d4 * 4 + 1) * 68 + 32 + kc2 * 2] = pack_bf16(va1.y, vb1.y);
        *(unsigned int*)&VtLds[0][(d4 * 4 + 2) * 68 + 32 + kc2 * 2] = pack_bf16(va1.z, vb1.z);
        *(unsigned int*)&VtLds[0][(d4 * 4 + 3) * 68 + 32 + kc2 * 2] = pack_bf16(va1.w, vb1.w);
    }
    __syncthreads();

    const float bias_d0  = btab[0];    // all d <= 0  -> bucket 0
    const float bias_far = btab[127];  // all d >= 113 -> bucket 31

    #pragma unroll 2
    for (int it = 0; it < 32; ++it) {
        const int cur = it & 1;
        const int kcb = it * 64;
        const unsigned short* Ks = KsLds[cur];
        const unsigned short* Vt = VtLds[cur];
        const bool pre = (it < 31);

        // ---- issue next-tile K loads EARLY (latency hides under QK/silu) ----
        float4 kx0, kx1, kx2, kx3;
        if (pre) {
            kx0 = *(const float4*)(kp);
            kx1 = *(const float4*)(kp + (size_t)16 * DMODEL);
            kx2 = *(const float4*)(kp + (size_t)32 * DMODEL);
            kx3 = *(const float4*)(kp + (size_t)48 * DMODEL);
            kp += (size_t)64 * DMODEL;
        }

        // ---- X^T = K * Q^T + bias (bias in accumulator init), two interleaved chains ----
        f32x16 st[2];
        #pragma unroll
        for (int t = 0; t < 2; ++t) {
            const int kcmin = kcb + t * 32;
            if (q0w + 31 - kcmin <= 0) {               // whole tile d<=0
                #pragma unroll
                for (int r = 0; r < 16; ++r) st[t][r] = bias_d0;
            } else if (q0w - (kcmin + 31) >= 113) {    // whole tile bucket 31
                #pragma unroll
                for (int r = 0; r < 16; ++r) st[t][r] = bias_far;
            } else {                                   // mixed band
                const int dql = q0w + l31 - kcmin - 4 * half;
                #pragma unroll
                for (int r = 0; r < 16; ++r) {
                    int dv = dql - ((r & 3) + 8 * (r >> 2));
                    dv = dv < 0 ? 0 : (dv > 127 ? 127 : dv);
                    st[t][r] = btab[dv];
                }
            }
        }

        __builtin_amdgcn_s_setprio(1);
        #pragma unroll
        for (int kf = 0; kf < 4; ++kf) {
            FragU ka0, ka1;
            {
                int off = l31 * 68 + kf * 16 + half * 8;
                ka0.u2[0] = *(const uint2*)&Ks[off];
                ka0.u2[1] = *(const uint2*)&Ks[off + 4];
                off += 32 * 68;
                ka1.u2[0] = *(const uint2*)&Ks[off];
                ka1.u2[1] = *(const uint2*)&Ks[off + 4];
            }
            st[0] = __builtin_amdgcn_mfma_f32_32x32x16_bf16(ka0.v, qf[kf].v, st[0], 0, 0, 0);
            st[1] = __builtin_amdgcn_mfma_f32_32x32x16_bf16(ka1.v, qf[kf].v, st[1], 0, 0, 0);
        }
        __builtin_amdgcn_s_setprio(0);

        // ---- sub-tile s0: silu(t=0) then PV(f=0,1) ----
        FragU pf0, pf1, pf2, pf3;
        {
            float vals[16];
            #pragma unroll
            for (int r = 0; r < 16; ++r) {
                float x = st[0][r];
                float e = __builtin_amdgcn_exp2f(-x);
                vals[r] = x * __builtin_amdgcn_rcpf(1.0f + e);
            }
            #pragma unroll
            for (int j = 0; j < 4; ++j) pf0.w[j] = pack_bf16(vals[2 * j], vals[2 * j + 1]);
            #pragma unroll
            for (int j = 0; j < 4; ++j) pf1.w[j] = pack_bf16(vals[8 + 2 * j], vals[9 + 2 * j]);
        }
        #pragma unroll
        for (int n = 0; n < 2; ++n) {
            FragU vf;
            int off = (n * 32 + l31) * 68 + half * 4;
            vf.u2[0] = *(const uint2*)&Vt[off];
            vf.u2[1] = *(const uint2*)&Vt[off + 8];
            oacc[n] = __builtin_amdgcn_mfma_f32_32x32x16_bf16(pf0.v, vf.v, oacc[n], 0, 0, 0);
        }
        #pragma unroll
        for (int n = 0; n < 2; ++n) {
            FragU vf;
            int off = (n * 32 + l31) * 68 + 16 + half * 4;
            vf.u2[0] = *(const uint2*)&Vt[off];
            vf.u2[1] = *(const uint2*)&Vt[off + 8];
            oacc[n] = __builtin_amdgcn_mfma_f32_32x32x16_bf16(pf1.v, vf.v, oacc[n], 0, 0, 0);
        }

        // ---- issue next-tile V loads (shorter liveness; covered by K-write+silu(s1)) ----
        float4 va0, vb0, va1, vb1;
        if (pre) {
            va0 = *(const float4*)(vp);
            vb0 = *(const float4*)(vp + DMODEL);
            va1 = *(const float4*)(vp + (size_t)32 * DMODEL);
            vb1 = *(const float4*)(vp + (size_t)32 * DMODEL + DMODEL);
            vp += (size_t)64 * DMODEL;
        }

        // ---- pack + ds_write next K tile (loads long done) ----
        if (pre) {
            const int nb = cur ^ 1;
            uint2 w;
            w.x = pack_bf16(kx0.x, kx0.y); w.y = pack_bf16(kx0.z, kx0.w);
            *(uint2*)&KsLds[nb][(krow +  0) * 68 + c4 * 4] = w;
            w.x = pack_bf16(kx1.x, kx1.y); w.y = pack_bf16(kx1.z, kx1.w);
            *(uint2*)&KsLds[nb][(krow + 16) * 68 + c4 * 4] = w;
            w.x = pack_bf16(kx2.x, kx2.y); w.y = pack_bf16(kx2.z, kx2.w);
            *(uint2*)&KsLds[nb][(krow + 32) * 68 + c4 * 4] = w;
            w.x = pack_bf16(kx3.x, kx3.y); w.y = pack_bf16(kx3.z, kx3.w);
            *(uint2*)&KsLds[nb][(krow + 48) * 68 + c4 * 4] = w;
        }

        // ---- sub-tile s1: silu(t=1) ----
        {
            float vals[16];
            #pragma unroll
            for (int r = 0; r < 16; ++r) {
                float x = st[1][r];
                float e = __builtin_amdgcn_exp2f(-x);
                vals[r] = x * __builtin_amdgcn_rcpf(1.0f + e);
            }
            #pragma unroll
            for (int j = 0; j < 4; ++j) pf2.w[j] = pack_bf16(vals[2 * j], vals[2 * j + 1]);
            #pragma unroll
            for (int j = 0; j < 4; ++j) pf3.w[j] = pack_bf16(vals[8 + 2 * j], vals[9 + 2 * j]);
        }

        // ---- pack + ds_write next V tile (V loads covered by K-write + silu) ----
        if (pre) {
            const int nb = cur ^ 1;
            *(unsigned int*)&VtLds[nb][(d4 * 4 + 0) * 68 + kc2 * 2]      = pack_bf16(va0.x, vb0.x);
            *(unsigned int*)&VtLds[nb][(d4 * 4 + 1) * 68 + kc2 * 2]      = pack_bf16(va0.y, vb0.y);
            *(unsigned int*)&VtLds[nb][(d4 * 4 + 2) * 68 + kc2 * 2]      = pack_bf16(va0.z, vb0.z);
            *(unsigned int*)&VtLds[nb][(d4 * 4 + 3) * 68 + kc2 * 2]      = pack_bf16(va0.w, vb0.w);
            *(unsigned int*)&VtLds[nb][(d4 * 4 + 0) * 68 + 32 + kc2 * 2] = pack_bf16(va1.x, vb1.x);
            *(unsigned int*)&VtLds[nb][(d4 * 4 + 1) * 68 + 32 + kc2 * 2] = pack_bf16(va1.y, vb1.y);
            *(unsigned int*)&VtLds[nb][(d4 * 4 + 2) * 68 + 32 + kc2 * 2] = pack_bf16(va1.z, vb1.z);
            *(unsigned int*)&VtLds[nb][(d4 * 4 + 3) * 68 + 32 + kc2 * 2] = pack_bf16(va1.w, vb1.w);
        }

        // ---- PV(f=2,3) ----
        #pragma unroll
        for (int n = 0; n < 2; ++n) {
            FragU vf;
            int off = (n * 32 + l31) * 68 + 32 + half * 4;
            vf.u2[0] = *(const uint2*)&Vt[off];
            vf.u2[1] = *(const uint2*)&Vt[off + 8];
            oacc[n] = __builtin_amdgcn_mfma_f32_32x32x16_bf16(pf2.v, vf.v, oacc[n], 0, 0, 0);
        }
        #pragma unroll
        for (int n = 0; n < 2; ++n) {
            FragU vf;
            int off = (n * 32 + l31) * 68 + 48 + half * 4;
            vf.u2[0] = *(const uint2*)&Vt[off];
            vf.u2[1] = *(const uint2*)&Vt[off + 8];
            oacc[n] = __builtin_amdgcn_mfma_f32_32x32x16_bf16(pf3.v, vf.v, oacc[n], 0, 0, 0);
        }

        // ---- single barrier per iter (4-wave domain; blocks drift freely) ----
        if (pre) __syncthreads();
    }

    // ---- store (x ln2): C layout row=q_local, col=d_local ----
    float* obase = Og + (size_t)(b * SEQ) * DMODEL + head * HD;
    #pragma unroll
    for (int r = 0; r < 16; ++r) {
        int q = q0w + (r & 3) + 8 * (r >> 2) + 4 * half;
        float* orow = obase + (size_t)q * DMODEL;
        #pragma unroll
        for (int n = 0; n < 2; ++n)
            orow[n * 32 + l31] = oacc[n][r] * LN2;
    }
}

extern "C" void kernel_launch(void* const* d_in, const int* in_sizes, int n_in,
                              void* d_out, int out_size, void* d_ws, size_t ws_size,
                              hipStream_t stream) {
    const float* v  = (const float*)d_in[0];
    const float* k  = (const float*)d_in[1];
    const float* q  = (const float*)d_in[2];
    const float* rw = (const float*)d_in[3];
    float* out = (float*)d_out;
    paa_kernel<<<dim3(1024), dim3(256), 0, stream>>>(v, k, q, rw, out);
}

// Round 10
// 216.305 us; speedup vs baseline: 1.7557x; 1.2909x over previous
//
#include <hip/hip_runtime.h>

#define SEQ 2048
#define NH 16
#define HD 64
#define DMODEL 1024

typedef short bf16x8 __attribute__((ext_vector_type(8)));
typedef float f32x16 __attribute__((ext_vector_type(16)));

union FragU {
    bf16x8 v;
    uint2 u2[2];
    unsigned int w[4];
    unsigned short s[8];
};

// Pack two f32 -> packed bf16 pair (lo in low 16 bits).
#if __has_builtin(__builtin_amdgcn_cvt_pk_bf16_f32)
typedef __bf16 v2bf_t __attribute__((ext_vector_type(2)));
__device__ __forceinline__ unsigned int pack_bf16(float lo, float hi) {
    union { v2bf_t h; unsigned int u; } cv;
    cv.h = __builtin_amdgcn_cvt_pk_bf16_f32(lo, hi);
    return cv.u;
}
#else
__device__ __forceinline__ unsigned int pack_bf16(float lo, float hi) {
    unsigned int a = __float_as_uint(lo) + 0x8000u;
    unsigned int b = __float_as_uint(hi) + 0x8000u;
    return __builtin_amdgcn_perm(b, a, 0x07060302);  // {b.hi16, a.hi16}
}
#endif

#define EXP_SCALE 1.44269504f   // 1/ln2, folded into Q and bias table
#define LN2       0.69314718f   // folded into epilogue store

// Block: 512 threads = 8 waves; each wave computes a 32q x 64d output tile
// (block covers 256 q for one (b,h)). Structure = round-4 proven best
// (126.5us rocprof): double-buffered K/V LDS tiles, ONE barrier per k-tile,
// next-tile global loads issued early, pack+ds_write late, two INTERLEAVED
// QK accumulator chains, setprio(1) around the QK MFMA cluster.
// Round-9 (silu-local only; every structural variant R5-R8 regressed):
//  a) pair-batched reciprocal: R01=rcp(a0*a1), val_i = x_i*a_other*R01 —
//     one v_rcp per TWO elements, no clamp needed (single a can't overflow;
//     pair overflow needs x0+x1<-127, ~7.8 sigma, and yields benign 0
//     vs true ~1e-15; no NaN path: R01=0 propagates through finite factors).
//  b) quarter-granularity silu->PV interleave: each PV MFMA pair issues as
//     soon as its 8 P-values exist, overlapping the next 8-elem trans burst.
__global__ __launch_bounds__(512, 4)
void paa_kernel(const float* __restrict__ Vg, const float* __restrict__ Kg,
                const float* __restrict__ Qg, const float* __restrict__ RW,
                float* __restrict__ Og)
{
    __shared__ __align__(16) unsigned short KsLds[2][64 * 68];  // [kc][d], stride 68
    __shared__ __align__(16) unsigned short VtLds[2][64 * 68];  // [d][kc], stride 68
    __shared__ float btab[128];  // 1.4427*bias by distance, clamped at 127

    const int tid  = threadIdx.x;
    const int lane = tid & 63;
    const int wave = tid >> 6;   // 0..7
    const int half = lane >> 5;
    const int l31  = lane & 31;

    const int bid  = blockIdx.x;
    const int bh   = bid & 63;
    const int qt   = bid >> 6;   // 0..7
    const int b    = bh >> 4;
    const int head = bh & 15;

    const int q0w = qt * 256 + wave * 32;   // 32 q rows per wave

    // ---- bias table (pre-scaled by 1/ln2) ----
    if (tid < 128) {
        int rp = tid;
        int bucket;
        if (rp < 16) bucket = rp;
        else {
            int big = 16 + (int)(logf((float)rp * 0.0625f) * 7.6943736f); // 16/ln(8)
            bucket = big < 31 ? big : 31;
        }
        btab[tid] = RW[bucket * NH + head] * EXP_SCALE;
    }

    // ---- preload Q fragments (B operand of S^T), pre-scaled by 1/ln2 ----
    FragU qf[4];
    {
        const float* qrow = Qg + (size_t)(b * SEQ + q0w + l31) * DMODEL + head * HD;
        #pragma unroll
        for (int kf = 0; kf < 4; ++kf) {
            int dd = kf * 16 + half * 8;
            float4 x0 = *(const float4*)(qrow + dd);
            float4 x1 = *(const float4*)(qrow + dd + 4);
            FragU f;
            f.w[0] = pack_bf16(x0.x * EXP_SCALE, x0.y * EXP_SCALE);
            f.w[1] = pack_bf16(x0.z * EXP_SCALE, x0.w * EXP_SCALE);
            f.w[2] = pack_bf16(x1.x * EXP_SCALE, x1.y * EXP_SCALE);
            f.w[3] = pack_bf16(x1.z * EXP_SCALE, x1.w * EXP_SCALE);
            qf[kf] = f;
        }
    }

    f32x16 oacc[2];
    #pragma unroll
    for (int n = 0; n < 2; ++n)
        #pragma unroll
        for (int r = 0; r < 16; ++r) oacc[n][r] = 0.0f;

    // staging geometry (512 threads stage a 64x64 tile of K and of V)
    const int krow = tid >> 4;   // 0..31 (+32 for second half)
    const int c4   = tid & 15;
    const int kc2  = tid >> 4;   // V: 2 kc rows at kc2*2
    const int d4   = tid & 15;   // V: 4 d cols at d4*4

    const float* kp = Kg + (size_t)(b * SEQ + krow) * DMODEL + head * HD + c4 * 4;
    const float* vp = Vg + (size_t)(b * SEQ + kc2 * 2) * DMODEL + head * HD + d4 * 4;

    // ---- prologue: stage tile 0 into buffer 0 ----
    {
        float4 k0 = *(const float4*)(kp);
        float4 k1 = *(const float4*)(kp + (size_t)32 * DMODEL);
        float4 v0 = *(const float4*)(vp);
        float4 v1 = *(const float4*)(vp + DMODEL);
        kp += (size_t)64 * DMODEL;
        vp += (size_t)64 * DMODEL;
        uint2 w;
        w.x = pack_bf16(k0.x, k0.y); w.y = pack_bf16(k0.z, k0.w);
        *(uint2*)&KsLds[0][krow * 68 + c4 * 4] = w;
        w.x = pack_bf16(k1.x, k1.y); w.y = pack_bf16(k1.z, k1.w);
        *(uint2*)&KsLds[0][(krow + 32) * 68 + c4 * 4] = w;
        *(unsigned int*)&VtLds[0][(d4 * 4 + 0) * 68 + kc2 * 2] = pack_bf16(v0.x, v1.x);
        *(unsigned int*)&VtLds[0][(d4 * 4 + 1) * 68 + kc2 * 2] = pack_bf16(v0.y, v1.y);
        *(unsigned int*)&VtLds[0][(d4 * 4 + 2) * 68 + kc2 * 2] = pack_bf16(v0.z, v1.z);
        *(unsigned int*)&VtLds[0][(d4 * 4 + 3) * 68 + kc2 * 2] = pack_bf16(v0.w, v1.w);
    }
    __syncthreads();

    const float bias_d0  = btab[0];    // all d <= 0  -> bucket 0
    const float bias_far = btab[127];  // all d >= 113 -> bucket 31

    // silu on 8 accumulator values (one bf16x8 A-fragment), pair-batched rcp.
    auto silu8 = [&](const f32x16& st, int base, FragU& pf) {
        float vals[8];
        #pragma unroll
        for (int g = 0; g < 4; ++g) {
            float x0 = st[base + 2 * g];
            float x1 = st[base + 2 * g + 1];
            float a0 = 1.0f + __builtin_amdgcn_exp2f(-x0);
            float a1 = 1.0f + __builtin_amdgcn_exp2f(-x1);
            float R01 = __builtin_amdgcn_rcpf(a0 * a1);
            vals[2 * g]     = x0 * a1 * R01;   // = x0 / a0
            vals[2 * g + 1] = x1 * a0 * R01;   // = x1 / a1
        }
        #pragma unroll
        for (int j = 0; j < 4; ++j) pf.w[j] = pack_bf16(vals[2 * j], vals[2 * j + 1]);
    };

    auto pv1 = [&](const unsigned short* Vt, int fbase, const FragU& pf) {
        #pragma unroll
        for (int n = 0; n < 2; ++n) {
            FragU vf;
            int off = (n * 32 + l31) * 68 + fbase + half * 4;
            vf.u2[0] = *(const uint2*)&Vt[off];      // kc offsets 4h..4h+3
            vf.u2[1] = *(const uint2*)&Vt[off + 8];  // kc offsets 4h+8..4h+11
            oacc[n] = __builtin_amdgcn_mfma_f32_32x32x16_bf16(pf.v, vf.v, oacc[n], 0, 0, 0);
        }
    };

    #pragma unroll 2
    for (int it = 0; it < 32; ++it) {
        const int cur = it & 1;
        const int kcb = it * 64;
        const unsigned short* Ks = KsLds[cur];
        const unsigned short* Vt = VtLds[cur];
        const bool pre = (it < 31);

        // ---- issue next-tile global loads EARLY (latency hides under compute) ----
        float4 k0, k1, v0, v1;
        if (pre) {
            k0 = *(const float4*)(kp);
            k1 = *(const float4*)(kp + (size_t)32 * DMODEL);
            v0 = *(const float4*)(vp);
            v1 = *(const float4*)(vp + DMODEL);
            kp += (size_t)64 * DMODEL;
            vp += (size_t)64 * DMODEL;
        }

        // ---- X^T = K * Q^T + bias (bias in accumulator init), two interleaved chains ----
        f32x16 st[2];
        #pragma unroll
        for (int t = 0; t < 2; ++t) {
            const int kcmin = kcb + t * 32;
            if (q0w + 31 - kcmin <= 0) {               // whole tile d<=0
                #pragma unroll
                for (int r = 0; r < 16; ++r) st[t][r] = bias_d0;
            } else if (q0w - (kcmin + 31) >= 113) {    // whole tile bucket 31
                #pragma unroll
                for (int r = 0; r < 16; ++r) st[t][r] = bias_far;
            } else {                                   // mixed band (~9% of tiles)
                const int dql = q0w + l31 - kcmin - 4 * half;
                #pragma unroll
                for (int r = 0; r < 16; ++r) {
                    int dv = dql - ((r & 3) + 8 * (r >> 2));
                    dv = dv < 0 ? 0 : (dv > 127 ? 127 : dv);
                    st[t][r] = btab[dv];
                }
            }
        }

        __builtin_amdgcn_s_setprio(1);
        #pragma unroll
        for (int kf = 0; kf < 4; ++kf) {
            FragU ka0, ka1;
            {
                int off = l31 * 68 + kf * 16 + half * 8;
                ka0.u2[0] = *(const uint2*)&Ks[off];
                ka0.u2[1] = *(const uint2*)&Ks[off + 4];
                off += 32 * 68;
                ka1.u2[0] = *(const uint2*)&Ks[off];
                ka1.u2[1] = *(const uint2*)&Ks[off + 4];
            }
            st[0] = __builtin_amdgcn_mfma_f32_32x32x16_bf16(ka0.v, qf[kf].v, st[0], 0, 0, 0);
            st[1] = __builtin_amdgcn_mfma_f32_32x32x16_bf16(ka1.v, qf[kf].v, st[1], 0, 0, 0);
        }
        __builtin_amdgcn_s_setprio(0);

        // ---- quarter-granularity: silu8 -> PV pair, x4, stage writes mid ----
        FragU pf0, pf1, pf2, pf3;
        silu8(st[0], 0, pf0);
        pv1(Vt, 0, pf0);
        silu8(st[0], 8, pf1);
        pv1(Vt, 16, pf1);

        // ---- pack + ds_write next tile into the other buffer (loads long done) ----
        if (pre) {
            const int nb = cur ^ 1;
            uint2 w;
            w.x = pack_bf16(k0.x, k0.y); w.y = pack_bf16(k0.z, k0.w);
            *(uint2*)&KsLds[nb][krow * 68 + c4 * 4] = w;
            w.x = pack_bf16(k1.x, k1.y); w.y = pack_bf16(k1.z, k1.w);
            *(uint2*)&KsLds[nb][(krow + 32) * 68 + c4 * 4] = w;
            *(unsigned int*)&VtLds[nb][(d4 * 4 + 0) * 68 + kc2 * 2] = pack_bf16(v0.x, v1.x);
            *(unsigned int*)&VtLds[nb][(d4 * 4 + 1) * 68 + kc2 * 2] = pack_bf16(v0.y, v1.y);
            *(unsigned int*)&VtLds[nb][(d4 * 4 + 2) * 68 + kc2 * 2] = pack_bf16(v0.z, v1.z);
            *(unsigned int*)&VtLds[nb][(d4 * 4 + 3) * 68 + kc2 * 2] = pack_bf16(v0.w, v1.w);
        }

        silu8(st[1], 0, pf2);
        pv1(Vt, 32, pf2);
        silu8(st[1], 8, pf3);
        pv1(Vt, 48, pf3);

        // ---- single barrier per iter: next buffer written, current reads done ----
        if (pre) __syncthreads();
    }

    // ---- store (x ln2): C layout row=q_local, col=d_local ----
    float* obase = Og + (size_t)(b * SEQ) * DMODEL + head * HD;
    #pragma unroll
    for (int r = 0; r < 16; ++r) {
        int q = q0w + (r & 3) + 8 * (r >> 2) + 4 * half;
        float* orow = obase + (size_t)q * DMODEL;
        #pragma unroll
        for (int n = 0; n < 2; ++n)
            orow[n * 32 + l31] = oacc[n][r] * LN2;
    }
}

extern "C" void kernel_launch(void* const* d_in, const int* in_sizes, int n_in,
                              void* d_out, int out_size, void* d_ws, size_t ws_size,
                              hipStream_t stream) {
    const float* v  = (const float*)d_in[0];
    const float* k  = (const float*)d_in[1];
    const float* q  = (const float*)d_in[2];
    const float* rw = (const float*)d_in[3];
    float* out = (float*)d_out;
    paa_kernel<<<dim3(512), dim3(512), 0, stream>>>(v, k, q, rw, out);
}